// Round 2
// baseline (563.555 us; speedup 1.0000x reference)
//
#include <hip/hip_runtime.h>

typedef __attribute__((ext_vector_type(8))) short bf16x8;
typedef __attribute__((ext_vector_type(4))) float f32x4;
typedef unsigned short u16;
typedef unsigned int   u32;

#define NTOK  196
#define NH    8
#define DVDIM 128
#define CDIM  512
#define DH    1024
// 32^-0.5 * log2(e)  (log2e folded into scale; bias table pre-scaled too)
#define SCALE2 0.25505654708103197f
#define NEG_BIG -1.0e30f
#define LOG2E 1.4426950408889634f
#define VSTRIDE 200   // vT row stride (elements); keeps all b128 loads 16B-aligned
// defer-rescale threshold (T13): skip O-rescale while max growth <= 8 (P <= 2^8, bf16-safe)
#define RESCALE_THR 8.0f

__device__ __forceinline__ u16 f2bf(float f) {
  u32 u = __builtin_bit_cast(u32, f);
  u32 r = u + 0x7FFFu + ((u >> 16) & 1u);   // RNE
  return (u16)(r >> 16);
}

// packed f32x2 -> bf16x2 (RNE), one VOP3 instead of 6 VALU ops (T12)
__device__ __forceinline__ u32 cvtpk(float lo, float hi) {
  u32 r;
  asm("v_cvt_pk_bf16_f32 %0, %1, %2" : "=v"(r) : "v"(lo), "v"(hi));
  return r;
}

// 16B async global->LDS; lds_wave_base must be wave-uniform (HW adds lane*16)
__device__ __forceinline__ void stage16(const void* g, char* lds_wave_base, int lane) {
#if __has_builtin(__builtin_amdgcn_global_load_lds)
  __builtin_amdgcn_global_load_lds(
      (const __attribute__((address_space(1))) unsigned int*)g,
      (__attribute__((address_space(3))) unsigned int*)lds_wave_base, 16, 0, 0);
#else
  *(uint4*)(lds_wave_base + lane * 16) = *(const uint4*)g;
#endif
}

// ---------------------------------------------------------------------------
// fp32 -> bf16 bulk convert (n8 = count/8, exact)
// ---------------------------------------------------------------------------
__global__ __launch_bounds__(256)
void cvt_k(const float* __restrict__ s, u16* __restrict__ d, int n8) {
  int i = blockIdx.x * 256 + threadIdx.x;
  if (i < n8) {
    const float4* sp = (const float4*)s + (size_t)i * 2;
    float4 a = sp[0], b = sp[1];
    uint4 o;
    o.x = (u32)f2bf(a.x) | ((u32)f2bf(a.y) << 16);
    o.y = (u32)f2bf(a.z) | ((u32)f2bf(a.w) << 16);
    o.z = (u32)f2bf(b.x) | ((u32)f2bf(b.y) << 16);
    o.w = (u32)f2bf(b.z) | ((u32)f2bf(b.w) << 16);
    ((uint4*)d)[i] = o;
  }
}

// ---------------------------------------------------------------------------
// biasT[h][key 256][query 224] = ab[h][bidx[query][key]] * LOG2E, pads -1e30
// ---------------------------------------------------------------------------
__global__ __launch_bounds__(224)
void biasT_k(const float* __restrict__ ab, const int* __restrict__ bidx,
             float* __restrict__ bT) {
  const int m = threadIdx.x, j = blockIdx.x, h = blockIdx.y;
  float v = NEG_BIG;
  if (j < NTOK && m < NTOK) v = ab[h * NTOK + bidx[m * NTOK + j]] * LOG2E;
  bT[((size_t)h * 256 + j) * 224 + m] = v;
}

// ---------------------------------------------------------------------------
// 128x128 MFMA GEMM (bf16 A,W; fp32 acc), global_load_lds staging.
// D[m][n] = sum_k A[m][k] W[n][k] + bias[n].
// 1-D grid, XCD swizzle: bid&7 -> xcd; blocks sharing an A panel adjacent.
// EPI 0: scatter q/k/vT bf16 workspace.  EPI 1: fp32 row-major + bias.
// ---------------------------------------------------------------------------
template<int K, int NB, int EPI>
__global__ __launch_bounds__(256)
void gemm_k(const u16* __restrict__ A, const u16* __restrict__ W,
            const float* __restrict__ bias,
            u16* __restrict__ q, u16* __restrict__ kk, u16* __restrict__ vT,
            float* __restrict__ out)
{
  __shared__ __align__(16) u16 As[128 * 32];
  __shared__ __align__(16) u16 Bs[128 * 32];
  const int tid  = threadIdx.x;
  const int bid  = blockIdx.x;
  const int xcd  = bid & 7, t = bid >> 3;
  const int bn   = t % NB, bm = xcd * 49 + t / NB;   // 392 = 8*49
  const int lane = tid & 63, w = tid >> 6;
  const int c16  = lane & 15, quad = lane >> 4;
  const int wm   = (w >> 1) * 64, wn = (w & 1) * 64;
  f32x4 acc[4][4] = {};

  const u16* Ab = A + (size_t)bm * 128 * K;
  const u16* Wb = W + (size_t)bn * 128 * K;
  char* ldsA = (char*)As + w * 1024;
  char* ldsB = (char*)Bs + w * 1024;

  for (int k0 = 0; k0 < K; k0 += 32) {
    #pragma unroll
    for (int p = 0; p < 2; ++p) {
      const int i = p * 256 + tid;
      const int m = i >> 2, kp = (i & 3) * 8;
      stage16(Ab + (size_t)m * K + k0 + kp, ldsA + p * 4096, lane);
      stage16(Wb + (size_t)m * K + k0 + kp, ldsB + p * 4096, lane);
    }
    __syncthreads();
    bf16x8 af[4], bfr[4];
    #pragma unroll
    for (int mi = 0; mi < 4; ++mi)
      af[mi] = *(const bf16x8*)&As[(wm + mi * 16 + c16) * 32 + quad * 8];
    #pragma unroll
    for (int ni = 0; ni < 4; ++ni)
      bfr[ni] = *(const bf16x8*)&Bs[(wn + ni * 16 + c16) * 32 + quad * 8];
    #pragma unroll
    for (int mi = 0; mi < 4; ++mi)
      #pragma unroll
      for (int ni = 0; ni < 4; ++ni)
        acc[mi][ni] = __builtin_amdgcn_mfma_f32_16x16x32_bf16(af[mi], bfr[ni], acc[mi][ni], 0, 0, 0);
    __syncthreads();
  }

  if (EPI == 0) {
    #pragma unroll
    for (int ni = 0; ni < 4; ++ni) {
      const int gn = bn * 128 + wn + ni * 16 + c16;
      const int h = gn / 192, d = gn - h * 192;
      const float bv = bias[gn];
      #pragma unroll
      for (int mi = 0; mi < 4; ++mi) {
        const int gm0 = bm * 128 + wm + mi * 16 + quad * 4;
        const int bb = gm0 / 196, tok0 = gm0 - bb * 196;  // tok0..tok0+3 same batch
        const size_t bhh = (size_t)bb * 8 + h;
        const float v0 = acc[mi][ni][0] + bv, v1 = acc[mi][ni][1] + bv;
        const float v2 = acc[mi][ni][2] + bv, v3 = acc[mi][ni][3] + bv;
        if (d < 64) {
          u16* dst = (d < 32) ? (q  + (bhh * 196 + tok0) * 32 + d)
                              : (kk + (bhh * 196 + tok0) * 32 + (d - 32));
          dst[0] = f2bf(v0); dst[32] = f2bf(v1); dst[64] = f2bf(v2); dst[96] = f2bf(v3);
        } else {
          ushort4 pk = { f2bf(v0), f2bf(v1), f2bf(v2), f2bf(v3) };
          *(ushort4*)&vT[(bhh * 128 + (d - 64)) * VSTRIDE + tok0] = pk;
        }
      }
    }
  } else {
    #pragma unroll
    for (int ni = 0; ni < 4; ++ni) {
      const int gn = bn * 128 + wn + ni * 16 + c16;
      const float bv = bias[gn];
      #pragma unroll
      for (int mi = 0; mi < 4; ++mi) {
        const int gm0 = bm * 128 + wm + mi * 16 + quad * 4;
        #pragma unroll
        for (int r = 0; r < 4; ++r)
          out[(size_t)(gm0 + r) * CDIM + gn] = acc[mi][ni][r] + bv;
      }
    }
  }
}

// ---------------------------------------------------------------------------
// Attention, S^T formulation. grid (2048 bh, 2 halves) x 256 threads.
// Latency-bound fix round: T14 reg-prefetch of next K/V chunk (global loads
// issued before current chunk's compute, LDS write between barriers),
// branchless dual-stream softmax (two query tiles interleave as straight-line
// code; dead tiles compute finite garbage, store guard unchanged), shared
// kf/bv fragments across the two streams (ds_read_b128 40->20 per chunk),
// T5 setprio around MFMA clusters. Regs pinned <=256 (2 waves/SIMD).
// ---------------------------------------------------------------------------
__global__ __launch_bounds__(256, 2)
void attn_k(const u16* __restrict__ q, const u16* __restrict__ kk,
            const u16* __restrict__ vT, const float* __restrict__ bT,
            u16* __restrict__ Ob)
{
  __shared__ __align__(16) u16 k_s[64 * 40];        // [key][kd], stride 40
  __shared__ __align__(16) u16 vt_s[128 * 72];      // [dv][key], stride 72
  __shared__ __align__(16) u16 p_s[2][4 * 16 * 72]; // per-stream per-wave [query][key]

  const int bh = blockIdx.x;
  const int b = bh >> 3, h = bh & 7;
  const int tid = threadIdx.x;
  const int lane = tid & 63, w = tid >> 6;
  const int c16 = lane & 15, quad = lane >> 4;
  const u16* qb = q  + (size_t)bh * (NTOK * 32);
  const u16* kb = kk + (size_t)bh * (NTOK * 32);
  const u16* vb = vT + (size_t)bh * (DVDIM * VSTRIDE);
  const float* bTh = bT + (size_t)h * 256 * 224;
  const int tmax = blockIdx.y ? 6 : 7;              // 13 tiles total, skip dead #13

  int qt[2]; bool act[2]; bf16x8 qf[2];
  #pragma unroll
  for (int s = 0; s < 2; ++s) {
    const int ti = w + 4 * s;
    act[s] = (ti < tmax);                           // store guard only
    qt[s] = blockIdx.y * 7 + ti;
    const int tok = min(qt[s] * 16 + c16, NTOK - 1);
    qf[s] = *(const bf16x8*)(qb + (size_t)tok * 32 + quad * 8);
  }
  float mx[2] = {NEG_BIG, NEG_BIG}, lsum[2] = {0.f, 0.f};
  f32x4 oacc[2][8] = {};
  const f32x4 zf = {0.f, 0.f, 0.f, 0.f};

  // staging-address constants (chunk-invariant)
  const int st_key_row = tid >> 2;                  // k_s row
  const int st_key_col = (tid & 3) * 8;             // k_s col (elements)
  const int st_dv[4] = { (tid >> 3), 32 + (tid >> 3), 64 + (tid >> 3), 96 + (tid >> 3) };
  const int st_kp = (tid & 7) * 8;                  // vt col part (elements)

  uint4 kreg, vreg[4];

  // T14 issue: global loads for chunk kc into registers (no wait)
  #define ISSUE(kc_) do {                                                     \
    const int key_ = min((kc_) * 64 + st_key_row, NTOK - 1);                  \
    kreg = *(const uint4*)(kb + (size_t)key_ * 32 + st_key_col);              \
    _Pragma("unroll")                                                         \
    for (int it = 0; it < 4; ++it) {                                          \
      const int col_ = min((kc_) * 64 + st_kp, 192);                          \
      vreg[it] = *(const uint4*)(vb + (size_t)st_dv[it] * VSTRIDE + col_);    \
    }                                                                         \
  } while (0)

  // T14 commit: registers -> LDS (compiler inserts vmcnt wait)
  #define COMMIT() do {                                                       \
    *(uint4*)&k_s[st_key_row * 40 + st_key_col] = kreg;                       \
    _Pragma("unroll")                                                         \
    for (int it = 0; it < 4; ++it)                                            \
      *(uint4*)&vt_s[st_dv[it] * 72 + st_kp] = vreg[it];                      \
  } while (0)

  ISSUE(0);
  COMMIT();
  __syncthreads();

  for (int kc = 0; kc < 4; ++kc) {
    if (kc < 3) ISSUE(kc + 1);                      // prefetch overlaps compute

    // ---- QK^T, both streams, shared K fragments
    bf16x8 kf4[4];
    #pragma unroll
    for (int nt = 0; nt < 4; ++nt)
      kf4[nt] = *(const bf16x8*)&k_s[(nt * 16 + c16) * 40 + quad * 8];
    f32x4 sc[2][4];
    __builtin_amdgcn_s_setprio(1);
    #pragma unroll
    for (int nt = 0; nt < 4; ++nt) {
      sc[0][nt] = __builtin_amdgcn_mfma_f32_16x16x32_bf16(kf4[nt], qf[0], zf, 0, 0, 0);
      sc[1][nt] = __builtin_amdgcn_mfma_f32_16x16x32_bf16(kf4[nt], qf[1], zf, 0, 0, 0);
    }
    __builtin_amdgcn_s_setprio(0);

    // ---- softmax, both streams straight-line (interleavable serial chains)
    float alpha2[2];
    #pragma unroll
    for (int s = 0; s < 2; ++s) {
      const int qg = min(qt[s] * 16 + c16, 223);    // clamp: dead tiles finite
      float ntmx[4];
      #pragma unroll
      for (int nt = 0; nt < 4; ++nt) {
        const float* bp = bTh + (size_t)(kc * 64 + nt * 16 + quad * 4) * 224 + qg;
        #pragma unroll
        for (int r = 0; r < 4; ++r)
          sc[s][nt][r] = sc[s][nt][r] * SCALE2 + bp[r * 224];
        ntmx[nt] = fmaxf(fmaxf(sc[s][nt][0], sc[s][nt][1]), fmaxf(sc[s][nt][2], sc[s][nt][3]));
      }
      const float cmx = fmaxf(fmaxf(ntmx[0], ntmx[1]), fmaxf(ntmx[2], ntmx[3]));

      // T13 defer-rescale (chunk 0 always fires; later chunks rarely)
      float alpha = 1.0f;
      if (__ballot(cmx > mx[s] + RESCALE_THR)) {
        float rmx = fmaxf(cmx, __shfl_xor(cmx, 16));
        rmx = fmaxf(rmx, __shfl_xor(rmx, 32));
        const float nmx = fmaxf(mx[s], rmx);
        alpha = exp2f(mx[s] - nmx);
        mx[s] = nmx;
        float a4[4];
        #pragma unroll
        for (int r = 0; r < 4; ++r) a4[r] = __shfl(alpha, quad * 4 + r);
        #pragma unroll
        for (int nt = 0; nt < 8; ++nt)
          #pragma unroll
          for (int r = 0; r < 4; ++r) oacc[s][nt][r] *= a4[r];
      }
      alpha2[s] = alpha;

      const float m = mx[s];                        // P = exp2(S-m) <= 2^THR
      float csum = 0.f;
      #pragma unroll
      for (int nt = 0; nt < 4; ++nt) {
        const float p0 = exp2f(sc[s][nt][0] - m), p1 = exp2f(sc[s][nt][1] - m);
        const float p2 = exp2f(sc[s][nt][2] - m), p3 = exp2f(sc[s][nt][3] - m);
        csum += (p0 + p1) + (p2 + p3);
        uint2 pk;
        pk.x = cvtpk(p0, p1);
        pk.y = cvtpk(p2, p3);
        *(uint2*)&p_s[s][(w * 16 + c16) * 72 + nt * 16 + quad * 4] = pk;
      }
      csum += __shfl_xor(csum, 16);
      csum += __shfl_xor(csum, 32);
      lsum[s] = lsum[s] * alpha2[s] + csum;
    }

    // ---- PV, both streams, shared V fragments (16 ds_reads not 32)
    __builtin_amdgcn_s_setprio(1);
    #pragma unroll
    for (int ks = 0; ks < 2; ++ks) {
      bf16x8 ap0 = *(const bf16x8*)&p_s[0][(w * 16 + c16) * 72 + ks * 32 + quad * 8];
      bf16x8 ap1 = *(const bf16x8*)&p_s[1][(w * 16 + c16) * 72 + ks * 32 + quad * 8];
      #pragma unroll
      for (int nt = 0; nt < 8; ++nt) {
        bf16x8 bv = *(const bf16x8*)&vt_s[(nt * 16 + c16) * 72 + ks * 32 + quad * 8];
        oacc[0][nt] = __builtin_amdgcn_mfma_f32_16x16x32_bf16(ap0, bv, oacc[0][nt], 0, 0, 0);
        oacc[1][nt] = __builtin_amdgcn_mfma_f32_16x16x32_bf16(ap1, bv, oacc[1][nt], 0, 0, 0);
      }
    }
    __builtin_amdgcn_s_setprio(0);

    if (kc < 3) {
      __syncthreads();                              // all waves done reading LDS
      COMMIT();                                     // write prefetched chunk
      __syncthreads();                              // visible to all
    }
  }
  #undef ISSUE
  #undef COMMIT

  #pragma unroll
  for (int s = 0; s < 2; ++s) {
    if (!act[s]) continue;
    float lr[4];
    #pragma unroll
    for (int r = 0; r < 4; ++r) lr[r] = __shfl(lsum[s], quad * 4 + r);
    #pragma unroll
    for (int r = 0; r < 4; ++r) {
      const int m = qt[s] * 16 + quad * 4 + r;
      if (m < NTOK) {
        const float inv = 1.0f / lr[r];
        #pragma unroll
        for (int nt = 0; nt < 8; ++nt)
          Ob[((size_t)b * NTOK + m) * DH + h * DVDIM + nt * 16 + c16] =
              f2bf(oacc[s][nt][r] * inv);
      }
    }
  }
}

// ---------------------------------------------------------------------------
extern "C" void kernel_launch(void* const* d_in, const int* in_sizes, int n_in,
                              void* d_out, int out_size, void* d_ws, size_t ws_size,
                              hipStream_t stream) {
  const float* x      = (const float*)d_in[0];   // (256,196,512)
  const float* qkv_w  = (const float*)d_in[1];   // (1536,512)
  const float* qkv_b  = (const float*)d_in[2];   // (1536,)
  const float* proj_w = (const float*)d_in[3];   // (512,1024)
  const float* proj_b = (const float*)d_in[4];   // (512,)
  const float* ab     = (const float*)d_in[5];   // (8,49)
  const int*   bidx   = (const int*)d_in[6];     // (196,196) int32
  float* out = (float*)d_out;                    // (256,196,512) fp32

  char* p = (char*)d_ws;
  u16*   qw  = (u16*)(p);                        // 25,690,112 B
  u16*   kw  = (u16*)(p + 25690112);             // 25,690,112 B
  u16*   vTw = (u16*)(p + 51380224);             // 104,857,600 B [bh][128][200]
  u16*   w1b = (u16*)(p + 156237824);            // 1,572,864 B
  u16*   w3b = (u16*)(p + 157810688);            // 1,048,576 B
  float* bT  = (float*)(p + 158859264);          // 1,835,008 B [8][256][224]
  u16*   xb  = (u16*)(p + 160694272);            // 51,380,224 B (dead after gemm1)
  u16*   Ob  = (u16*)(p + 160694272);            // 102,760,448 B (aliases xb; safe)

  // precompute: bf16 casts + bias table
  cvt_k<<<12544, 256, 0, stream>>>(x,      xb,  3211264);
  cvt_k<<<  384, 256, 0, stream>>>(qkv_w,  w1b,   98304);
  cvt_k<<<  256, 256, 0, stream>>>(proj_w, w3b,   65536);
  biasT_k<<<dim3(256, 8), 224, 0, stream>>>(ab, bidx, bT);

  // QKV GEMM: M=50176(392), N=1536(12), K=512 ; scatter q/k/vT
  gemm_k<512, 12, 0><<<4704, 256, 0, stream>>>(xb, w1b, qkv_b, qw, kw, vTw, nullptr);

  // attention
  attn_k<<<dim3(2048, 2), 256, 0, stream>>>(qw, kw, vTw, bT, Ob);

  // proj GEMM: M=50176, N=512(4), K=1024 ; fp32 out + bias
  gemm_k<1024, 4, 1><<<1568, 256, 0, stream>>>(Ob, w3b, proj_b, nullptr, nullptr, nullptr, out);
}

// Round 3
// 540.472 us; speedup vs baseline: 1.0427x; 1.0427x over previous
//
#include <hip/hip_runtime.h>

typedef __attribute__((ext_vector_type(8))) short bf16x8;
typedef __attribute__((ext_vector_type(4))) float f32x4;
typedef unsigned short u16;
typedef unsigned int   u32;

#define NTOK  196
#define NH    8
#define DVDIM 128
#define CDIM  512
#define DH    1024
// 32^-0.5 * log2(e)  (log2e folded into scale; bias table pre-scaled too)
#define SCALE2 0.25505654708103197f
#define NEG_BIG -1.0e30f
#define LOG2E 1.4426950408889634f
#define VSTRIDE 200   // vT row stride (elements); keeps all b128 loads 16B-aligned
// defer-rescale threshold (T13): skip O-rescale while max growth <= 8 (P <= 2^8, bf16-safe)
#define RESCALE_THR 8.0f

__device__ __forceinline__ u16 f2bf(float f) {
  u32 u = __builtin_bit_cast(u32, f);
  u32 r = u + 0x7FFFu + ((u >> 16) & 1u);   // RNE
  return (u16)(r >> 16);
}

// packed f32x2 -> bf16x2 (RNE), one VOP3 instead of 6 VALU ops (T12)
__device__ __forceinline__ u32 cvtpk(float lo, float hi) {
  u32 r;
  asm("v_cvt_pk_bf16_f32 %0, %1, %2" : "=v"(r) : "v"(lo), "v"(hi));
  return r;
}

// 16B async global->LDS; lds_wave_base must be wave-uniform (HW adds lane*16)
__device__ __forceinline__ void stage16(const void* g, char* lds_wave_base, int lane) {
#if __has_builtin(__builtin_amdgcn_global_load_lds)
  __builtin_amdgcn_global_load_lds(
      (const __attribute__((address_space(1))) unsigned int*)g,
      (__attribute__((address_space(3))) unsigned int*)lds_wave_base, 16, 0, 0);
#else
  *(uint4*)(lds_wave_base + lane * 16) = *(const uint4*)g;
#endif
}

// ---------------------------------------------------------------------------
// fp32 -> bf16 bulk convert (n8 = count/8, exact)
// ---------------------------------------------------------------------------
__global__ __launch_bounds__(256)
void cvt_k(const float* __restrict__ s, u16* __restrict__ d, int n8) {
  int i = blockIdx.x * 256 + threadIdx.x;
  if (i < n8) {
    const float4* sp = (const float4*)s + (size_t)i * 2;
    float4 a = sp[0], b = sp[1];
    uint4 o;
    o.x = (u32)f2bf(a.x) | ((u32)f2bf(a.y) << 16);
    o.y = (u32)f2bf(a.z) | ((u32)f2bf(a.w) << 16);
    o.z = (u32)f2bf(b.x) | ((u32)f2bf(b.y) << 16);
    o.w = (u32)f2bf(b.z) | ((u32)f2bf(b.w) << 16);
    ((uint4*)d)[i] = o;
  }
}

// ---------------------------------------------------------------------------
// biasT[h][key 256][query 224] = ab[h][bidx[query][key]] * LOG2E, pads -1e30
// ---------------------------------------------------------------------------
__global__ __launch_bounds__(224)
void biasT_k(const float* __restrict__ ab, const int* __restrict__ bidx,
             float* __restrict__ bT) {
  const int m = threadIdx.x, j = blockIdx.x, h = blockIdx.y;
  float v = NEG_BIG;
  if (j < NTOK && m < NTOK) v = ab[h * NTOK + bidx[m * NTOK + j]] * LOG2E;
  bT[((size_t)h * 256 + j) * 224 + m] = v;
}

// ---------------------------------------------------------------------------
// 128x128 MFMA GEMM (bf16 A,W; fp32 acc), global_load_lds staging.
// D[m][n] = sum_k A[m][k] W[n][k] + bias[n].
// 1-D grid, XCD swizzle: bid&7 -> xcd; blocks sharing an A panel adjacent.
// EPI 0: scatter q/k/vT bf16 workspace.  EPI 1: fp32 row-major + bias.
// ---------------------------------------------------------------------------
template<int K, int NB, int EPI>
__global__ __launch_bounds__(256)
void gemm_k(const u16* __restrict__ A, const u16* __restrict__ W,
            const float* __restrict__ bias,
            u16* __restrict__ q, u16* __restrict__ kk, u16* __restrict__ vT,
            float* __restrict__ out)
{
  __shared__ __align__(16) u16 As[128 * 32];
  __shared__ __align__(16) u16 Bs[128 * 32];
  const int tid  = threadIdx.x;
  const int bid  = blockIdx.x;
  const int xcd  = bid & 7, t = bid >> 3;
  const int bn   = t % NB, bm = xcd * 49 + t / NB;   // 392 = 8*49
  const int lane = tid & 63, w = tid >> 6;
  const int c16  = lane & 15, quad = lane >> 4;
  const int wm   = (w >> 1) * 64, wn = (w & 1) * 64;
  f32x4 acc[4][4] = {};

  const u16* Ab = A + (size_t)bm * 128 * K;
  const u16* Wb = W + (size_t)bn * 128 * K;
  char* ldsA = (char*)As + w * 1024;
  char* ldsB = (char*)Bs + w * 1024;

  for (int k0 = 0; k0 < K; k0 += 32) {
    #pragma unroll
    for (int p = 0; p < 2; ++p) {
      const int i = p * 256 + tid;
      const int m = i >> 2, kp = (i & 3) * 8;
      stage16(Ab + (size_t)m * K + k0 + kp, ldsA + p * 4096, lane);
      stage16(Wb + (size_t)m * K + k0 + kp, ldsB + p * 4096, lane);
    }
    __syncthreads();
    bf16x8 af[4], bfr[4];
    #pragma unroll
    for (int mi = 0; mi < 4; ++mi)
      af[mi] = *(const bf16x8*)&As[(wm + mi * 16 + c16) * 32 + quad * 8];
    #pragma unroll
    for (int ni = 0; ni < 4; ++ni)
      bfr[ni] = *(const bf16x8*)&Bs[(wn + ni * 16 + c16) * 32 + quad * 8];
    #pragma unroll
    for (int mi = 0; mi < 4; ++mi)
      #pragma unroll
      for (int ni = 0; ni < 4; ++ni)
        acc[mi][ni] = __builtin_amdgcn_mfma_f32_16x16x32_bf16(af[mi], bfr[ni], acc[mi][ni], 0, 0, 0);
    __syncthreads();
  }

  if (EPI == 0) {
    #pragma unroll
    for (int ni = 0; ni < 4; ++ni) {
      const int gn = bn * 128 + wn + ni * 16 + c16;
      const int h = gn / 192, d = gn - h * 192;
      const float bv = bias[gn];
      #pragma unroll
      for (int mi = 0; mi < 4; ++mi) {
        const int gm0 = bm * 128 + wm + mi * 16 + quad * 4;
        const int bb = gm0 / 196, tok0 = gm0 - bb * 196;  // tok0..tok0+3 same batch
        const size_t bhh = (size_t)bb * 8 + h;
        const float v0 = acc[mi][ni][0] + bv, v1 = acc[mi][ni][1] + bv;
        const float v2 = acc[mi][ni][2] + bv, v3 = acc[mi][ni][3] + bv;
        if (d < 64) {
          u16* dst = (d < 32) ? (q  + (bhh * 196 + tok0) * 32 + d)
                              : (kk + (bhh * 196 + tok0) * 32 + (d - 32));
          dst[0] = f2bf(v0); dst[32] = f2bf(v1); dst[64] = f2bf(v2); dst[96] = f2bf(v3);
        } else {
          ushort4 pk = { f2bf(v0), f2bf(v1), f2bf(v2), f2bf(v3) };
          *(ushort4*)&vT[(bhh * 128 + (d - 64)) * VSTRIDE + tok0] = pk;
        }
      }
    }
  } else {
    #pragma unroll
    for (int ni = 0; ni < 4; ++ni) {
      const int gn = bn * 128 + wn + ni * 16 + c16;
      const float bv = bias[gn];
      #pragma unroll
      for (int mi = 0; mi < 4; ++mi) {
        const int gm0 = bm * 128 + wm + mi * 16 + quad * 4;
        #pragma unroll
        for (int r = 0; r < 4; ++r)
          out[(size_t)(gm0 + r) * CDIM + gn] = acc[mi][ni][r] + bv;
      }
    }
  }
}

// ---------------------------------------------------------------------------
// Attention, S^T formulation. grid (2048 bh, 4 quarter-slabs) x 256 threads.
// Occupancy round: ONE query tile per wave (oacc 64->32 AGPRs, one qf/sc)
// so unified reg count drops ~180 -> ~125 => 3-4 waves/SIMD, 4 blocks/CU
// resident (LDS 32KB x4 = 128KB). Cross-block TLP hides the staging/barrier
// latency that R1/R2 could not hide in-wave. Dead tiles (3/16) skip compute
// via wave-uniform act branch. Keeps T13 defer-rescale, T12 cvtpk, T5
// setprio, max3 tree. No reg-prefetch, no forced launch-bounds (R2 spill).
// ---------------------------------------------------------------------------
__global__ __launch_bounds__(256)
void attn_k(const u16* __restrict__ q, const u16* __restrict__ kk,
            const u16* __restrict__ vT, const float* __restrict__ bT,
            u16* __restrict__ Ob)
{
  __shared__ __align__(16) u16 k_s[64 * 40];        // [key][kd], stride 40
  __shared__ __align__(16) u16 vt_s[128 * 72];      // [dv][key], stride 72
  __shared__ __align__(16) u16 p_s[4 * 16 * 72];    // per-wave [query][key]

  const int bh = blockIdx.x;
  const int b = bh >> 3, h = bh & 7;
  const int tid = threadIdx.x;
  const int lane = tid & 63, w = tid >> 6;
  const int c16 = lane & 15, quad = lane >> 4;
  const u16* qb = q  + (size_t)bh * (NTOK * 32);
  const u16* kb = kk + (size_t)bh * (NTOK * 32);
  const u16* vb = vT + (size_t)bh * (DVDIM * VSTRIDE);
  const float* bTh = bT + (size_t)h * 256 * 224;

  const int ti  = blockIdx.y * 4 + w;               // 16 slots, 13 live tiles
  const bool act = (ti < 13);                       // wave-uniform
  const int tok = min(ti * 16 + c16, NTOK - 1);
  const bf16x8 qf = *(const bf16x8*)(qb + (size_t)tok * 32 + quad * 8);
  float mx = NEG_BIG, lsum = 0.f;
  f32x4 oacc[8] = {};
  const f32x4 zf = {0.f, 0.f, 0.f, 0.f};
  u16* pw = p_s + w * 16 * 72;

  for (int kc = 0; kc < 4; ++kc) {
    {  // K chunk: 64 keys x 32 kd, b128 (dup key 195 for rows >195; bias kills)
      const int key = min(kc * 64 + (tid >> 2), NTOK - 1);
      const int part = (tid & 3) * 8;
      *(uint4*)&k_s[(tid >> 2) * 40 + part] = *(const uint4*)(kb + (size_t)key * 32 + part);
    }
    #pragma unroll
    for (int it = 0; it < 4; ++it) {
      // V^T chunk: 128 dv x 64 keys, row-contiguous b128.
      // col clamp to 192: kc<3 exact; kc=3 places keys 192..195 exactly;
      // pad cols (keys>=196) read in-row pad bytes (finite) * P=0.
      const int idx = tid + it * 256;
      const int dv = idx >> 3, kp = (idx & 7) * 8;
      const int col = min(kc * 64 + kp, 192);
      *(uint4*)&vt_s[dv * 72 + kp] = *(const uint4*)(vb + (size_t)dv * VSTRIDE + col);
    }
    __syncthreads();

    if (act) {
      // ---- QK^T: S^T[key][query] = K*Q^T
      f32x4 sc[4];
      __builtin_amdgcn_s_setprio(1);
      #pragma unroll
      for (int nt = 0; nt < 4; ++nt) {
        bf16x8 kf = *(const bf16x8*)&k_s[(nt * 16 + c16) * 40 + quad * 8];
        sc[nt] = __builtin_amdgcn_mfma_f32_16x16x32_bf16(kf, qf, zf, 0, 0, 0);
      }
      __builtin_amdgcn_s_setprio(0);

      // ---- softmax (per query column c16; state in lane groups of 4)
      const int qg = min(ti * 16 + c16, 223);       // clamp: tile 12 pad finite
      float ntmx[4];
      #pragma unroll
      for (int nt = 0; nt < 4; ++nt) {
        const float* bp = bTh + (size_t)(kc * 64 + nt * 16 + quad * 4) * 224 + qg;
        #pragma unroll
        for (int r = 0; r < 4; ++r)
          sc[nt][r] = sc[nt][r] * SCALE2 + bp[r * 224];
        ntmx[nt] = fmaxf(fmaxf(sc[nt][0], sc[nt][1]), fmaxf(sc[nt][2], sc[nt][3]));
      }
      const float cmx = fmaxf(fmaxf(ntmx[0], ntmx[1]), fmaxf(ntmx[2], ntmx[3]));

      // T13 defer-rescale (chunk 0 always fires; later chunks rarely)
      float alpha = 1.0f;
      if (__ballot(cmx > mx + RESCALE_THR)) {
        float rmx = fmaxf(cmx, __shfl_xor(cmx, 16));
        rmx = fmaxf(rmx, __shfl_xor(rmx, 32));
        const float nmx = fmaxf(mx, rmx);
        alpha = exp2f(mx - nmx);
        mx = nmx;
        float a4[4];
        #pragma unroll
        for (int r = 0; r < 4; ++r) a4[r] = __shfl(alpha, quad * 4 + r);
        #pragma unroll
        for (int nt = 0; nt < 8; ++nt)
          #pragma unroll
          for (int r = 0; r < 4; ++r) oacc[nt][r] *= a4[r];
      }

      const float m = mx;                           // P = exp2(S-m) <= 2^THR
      float csum = 0.f;
      #pragma unroll
      for (int nt = 0; nt < 4; ++nt) {
        const float p0 = exp2f(sc[nt][0] - m), p1 = exp2f(sc[nt][1] - m);
        const float p2 = exp2f(sc[nt][2] - m), p3 = exp2f(sc[nt][3] - m);
        csum += (p0 + p1) + (p2 + p3);
        uint2 pk;
        pk.x = cvtpk(p0, p1);                       // T12
        pk.y = cvtpk(p2, p3);
        *(uint2*)&pw[c16 * 72 + nt * 16 + quad * 4] = pk;
      }
      csum += __shfl_xor(csum, 16);
      csum += __shfl_xor(csum, 32);
      lsum = lsum * alpha + csum;

      // ---- PV: O += P * V (same-wave LDS round-trip: in order)
      __builtin_amdgcn_s_setprio(1);
      #pragma unroll
      for (int ks = 0; ks < 2; ++ks) {
        bf16x8 ap = *(const bf16x8*)&pw[c16 * 72 + ks * 32 + quad * 8];
        #pragma unroll
        for (int nt = 0; nt < 8; ++nt) {
          bf16x8 bv = *(const bf16x8*)&vt_s[(nt * 16 + c16) * 72 + ks * 32 + quad * 8];
          oacc[nt] = __builtin_amdgcn_mfma_f32_16x16x32_bf16(ap, bv, oacc[nt], 0, 0, 0);
        }
      }
      __builtin_amdgcn_s_setprio(0);
    }
    __syncthreads();
  }

  if (act) {
    float lr[4];
    #pragma unroll
    for (int r = 0; r < 4; ++r) lr[r] = __shfl(lsum, quad * 4 + r);
    #pragma unroll
    for (int r = 0; r < 4; ++r) {
      const int m = ti * 16 + quad * 4 + r;
      if (m < NTOK) {
        const float inv = 1.0f / lr[r];
        #pragma unroll
        for (int nt = 0; nt < 8; ++nt)
          Ob[((size_t)b * NTOK + m) * DH + h * DVDIM + nt * 16 + c16] =
              f2bf(oacc[nt][r] * inv);
      }
    }
  }
}

// ---------------------------------------------------------------------------
extern "C" void kernel_launch(void* const* d_in, const int* in_sizes, int n_in,
                              void* d_out, int out_size, void* d_ws, size_t ws_size,
                              hipStream_t stream) {
  const float* x      = (const float*)d_in[0];   // (256,196,512)
  const float* qkv_w  = (const float*)d_in[1];   // (1536,512)
  const float* qkv_b  = (const float*)d_in[2];   // (1536,)
  const float* proj_w = (const float*)d_in[3];   // (512,1024)
  const float* proj_b = (const float*)d_in[4];   // (512,)
  const float* ab     = (const float*)d_in[5];   // (8,49)
  const int*   bidx   = (const int*)d_in[6];     // (196,196) int32
  float* out = (float*)d_out;                    // (256,196,512) fp32

  char* p = (char*)d_ws;
  u16*   qw  = (u16*)(p);                        // 25,690,112 B
  u16*   kw  = (u16*)(p + 25690112);             // 25,690,112 B
  u16*   vTw = (u16*)(p + 51380224);             // 104,857,600 B [bh][128][200]
  u16*   w1b = (u16*)(p + 156237824);            // 1,572,864 B
  u16*   w3b = (u16*)(p + 157810688);            // 1,048,576 B
  float* bT  = (float*)(p + 158859264);          // 1,835,008 B [8][256][224]
  u16*   xb  = (u16*)(p + 160694272);            // 51,380,224 B (dead after gemm1)
  u16*   Ob  = (u16*)(p + 160694272);            // 102,760,448 B (aliases xb; safe)

  // precompute: bf16 casts + bias table
  cvt_k<<<12544, 256, 0, stream>>>(x,      xb,  3211264);
  cvt_k<<<  384, 256, 0, stream>>>(qkv_w,  w1b,   98304);
  cvt_k<<<  256, 256, 0, stream>>>(proj_w, w3b,   65536);
  biasT_k<<<dim3(256, 8), 224, 0, stream>>>(ab, bidx, bT);

  // QKV GEMM: M=50176(392), N=1536(12), K=512 ; scatter q/k/vT
  gemm_k<512, 12, 0><<<4704, 256, 0, stream>>>(xb, w1b, qkv_b, qw, kw, vTw, nullptr);

  // attention: 1 tile/wave, 4 blocks per bh
  attn_k<<<dim3(2048, 4), 256, 0, stream>>>(qw, kw, vTw, bT, Ob);

  // proj GEMM: M=50176, N=512(4), K=1024 ; fp32 out + bias
  gemm_k<1024, 4, 1><<<1568, 256, 0, stream>>>(Ob, w3b, proj_b, nullptr, nullptr, nullptr, out);
}